// Round 3
// baseline (636.533 us; speedup 1.0000x reference)
//
#include <hip/hip_runtime.h>
#include <hip/hip_fp16.h>
#include <cstdint>
#include <cstddef>

using u16 = unsigned short;
using u32 = unsigned int;

typedef _Float16 half8 __attribute__((ext_vector_type(8)));
typedef float f32x4 __attribute__((ext_vector_type(4)));

#define MF(a, b, c) __builtin_amdgcn_mfma_f32_16x16x32_f16((a), (b), (c), 0, 0, 0)

static inline int cdiv(int a, int b) { return (a + b - 1) / b; }

// ===========================================================================
// prep_k: fused zero-init + weight panelization + rule precompute.
// ===========================================================================

__global__ void prep_k(const float* __restrict__ Wr,
                       const float* __restrict__ Ws, const float* __restrict__ br,
                       const float* __restrict__ W_in, const float* __restrict__ W_h1,
                       const float* __restrict__ W_h2,
                       const float* __restrict__ centers, const float* __restrict__ logsig,
                       u16* __restrict__ wcat,
                       u16* __restrict__ winp, u16* __restrict__ wh1p,
                       u16* __restrict__ wh2p,
                       u16* __restrict__ pcB, float* __restrict__ pccc,
                       int* __restrict__ zerobase, int nzero,
                       int Z, int Wb) {
    const int bid = blockIdx.x;
    const int tid = threadIdx.x;
    if (bid < Z) {                                   // zero-init region
        int i = bid * 256 + tid;
        if (i < nzero) zerobase[i] = 0;
        return;
    }
    if (bid < Z + Wb) {                              // wcat panels [552][256][8] x3 layers
        size_t t = (size_t)(bid - Z) * 256 + tid;
        const size_t PL = 552u * 256u * 8u;
        int l = (int)(t / PL);
        size_t rem = t - (size_t)l * PL;
        int kp = (int)(rem >> 11);
        int o = (int)((rem >> 3) & 255);
        int e = (int)(rem & 7);
        int k = kp * 8 + e;
        float v;
        if (k < 4096)      v = Wr[((((size_t)l * 16 + (k >> 8)) * 256) + (k & 255)) * 256 + o];
        else if (k < 4352) v = Ws[(((size_t)l * 256) + (k - 4096)) * 256 + o];
        else if (k < 4368) v = br[(((size_t)l * 16) + (k - 4352)) * 256 + o];
        else               v = 0.f;
        union { u16 u; _Float16 h; } c; c.h = (_Float16)v;
        wcat[t] = c.u;
        return;
    }
    if (bid < Z + Wb + 128) {                        // panelize W_in (K=128,M=256)
        size_t t = (size_t)(bid - Z - Wb) * 256 + tid;
        int e = (int)(t & 7), o = (int)((t >> 3) & 255);
        int kp = (int)(t >> 11);
        union { u16 u; _Float16 h; } c; c.h = (_Float16)W_in[(size_t)(kp * 8 + e) * 256 + o];
        winp[t] = c.u;
        return;
    }
    if (bid < Z + Wb + 256) {                        // panelize W_h1 (K=256,M=128)
        size_t t = (size_t)(bid - Z - Wb - 128) * 256 + tid;
        int e = (int)(t & 7), o = (int)((t >> 3) & 127);
        int kp = (int)(t >> 10);
        union { u16 u; _Float16 h; } c; c.h = (_Float16)W_h1[(size_t)(kp * 8 + e) * 128 + o];
        wh1p[t] = c.u;
        return;
    }
    if (bid < Z + Wb + 256 + 24) {                   // panelize W_h2 (K=128,M=40->48 pad)
        int t = (bid - Z - Wb - 256) * 256 + tid;    // 16*48*8 = 6144
        int e = t & 7, col = (t >> 3) % 48, p = t / 384;
        int k = p * 8 + e;
        float v = (col < 40) ? W_h2[(size_t)k * 40 + col] : 0.f;
        union { u16 u; _Float16 h; } c; c.h = (_Float16)v;
        wh2p[t] = c.u;
        return;
    }
    {                                                // pc_build: 48 blocks (l*16+r)
        int lr = bid - (Z + Wb + 256 + 24);
        size_t idx = (size_t)lr * 256 + tid;
        float ls = logsig[idx];
        float inv = expf(-2.f * ls);
        float c = centers[idx];
        union { u16 u; _Float16 h; } c1, c2;
        c1.h = (_Float16)inv;
        c2.h = (_Float16)(-2.f * c * inv);
        pcB[(size_t)lr * 512 + tid] = c1.u;          // B[k][r] = inv_s2[r][k], k<256
        pcB[(size_t)lr * 512 + 256 + tid] = c2.u;    // B[256+k][r] = -2 c inv
        __shared__ float sm[256];
        sm[tid] = c * c * inv;
        __syncthreads();
        for (int s = 128; s > 0; s >>= 1) { if (tid < s) sm[tid] += sm[tid + s]; __syncthreads(); }
        if (tid == 0) pccc[lr] = sm[0];
    }
}

// ===========================================================================
// fused_k: the whole network in ONE persistent kernel.
// Block owns 128 rows; h lives in LDS [128][264] f16 the whole time.
// B-operands are MFMA-fragment loads straight from global (L2-resident).
// Grid barriers (manual, atomic counter; all blocks co-resident at
// __launch_bounds__(256,2): grid 391 <= 512 slots) only for:
//   per layer: firing-flag consensus, BN stats. Cold path adds uniform extras.
// Hot path global traffic: x read + weights + out write. No h16/pre16/agg16.
// ===========================================================================

__launch_bounds__(256, 2)
__global__ void fused_k(const float* __restrict__ x,
                        const int* __restrict__ esrc, const int* __restrict__ edst,
                        const u16* __restrict__ winp, const float* __restrict__ b_in,
                        const u16* __restrict__ wcat, const float* __restrict__ b_self,
                        const u16* __restrict__ pcB, const float* __restrict__ pccc,
                        const float* __restrict__ gamma, const float* __restrict__ beta,
                        const u16* __restrict__ wh1p, const float* __restrict__ b_h1,
                        const u16* __restrict__ wh2p, const float* __restrict__ b_h2,
                        float* __restrict__ outF,
                        u16* __restrict__ h16, u16* __restrict__ agg16,
                        int* __restrict__ deg, int* __restrict__ indptr,
                        int* __restrict__ cursor, float* __restrict__ deginv,
                        int* __restrict__ ssrc,
                        int* __restrict__ gflag, int* __restrict__ done,
                        int* __restrict__ barctr, float* __restrict__ bnsum,
                        int E, int n, int nb) {
    __shared__ __align__(16) u16 h_s[128 * 264];   // 67584 B, row stride 264 (528B, 16-aligned)
    __shared__ __align__(16) u16 mu_s[128 * 16];   // 4096 B
    __shared__ __align__(16) u16 scr[4096];        // 8192 B: x-stage [128][32] / bnbuf / l_ab / scan
    __shared__ int sfl;

    const int tid = threadIdx.x;
    const int bid = blockIdx.x;
    const int row0 = bid * 128;
    const int lane = tid & 63;
    const int q = lane >> 4, mm = lane & 15;
    const int wave = tid >> 6;
    int nr = n - row0; if (nr > 128) nr = 128;
    const int rA0 = wave * 32 + mm;
    const int rA1 = rA0 + 16;
    int bseq = 0;

    auto gbar = [&]() {
        __threadfence();
        __syncthreads();
        ++bseq;
        if (tid == 0) {
            atomicAdd(barctr, 1);
            while (atomicAdd(barctr, 0) < nb * bseq) __builtin_amdgcn_s_sleep(2);
        }
        __syncthreads();
    };

    f32x4 acc[2][16];

    // ================= GEMM0: h = relu(x @ W_in + b_in), K=128 =================
#pragma unroll
    for (int i = 0; i < 2; ++i)
#pragma unroll
        for (int j = 0; j < 16; ++j) acc[i][j] = (f32x4){0.f, 0.f, 0.f, 0.f};

    for (int c = 0; c < 4; ++c) {                  // K chunks of 32
#pragma unroll
        for (int it = 0; it < 2; ++it) {
            int idx = it * 256 + tid;              // 0..511
            int row = idx >> 2, kk = (idx & 3) * 8;
            int grow = row0 + row; if (grow >= n) grow = n - 1;
            const float* xr = x + (size_t)grow * 128 + c * 32 + kk;
            float4 f0 = *(const float4*)xr;
            float4 f1 = *(const float4*)(xr + 4);
            union { uint4 u4; _Float16 h[8]; } cv;
            cv.h[0] = (_Float16)f0.x; cv.h[1] = (_Float16)f0.y;
            cv.h[2] = (_Float16)f0.z; cv.h[3] = (_Float16)f0.w;
            cv.h[4] = (_Float16)f1.x; cv.h[5] = (_Float16)f1.y;
            cv.h[6] = (_Float16)f1.z; cv.h[7] = (_Float16)f1.w;
            *(uint4*)(scr + row * 32 + kk) = cv.u4;
        }
        __syncthreads();
        {
            half8 af0 = *(const half8*)(scr + rA0 * 32 + q * 8);
            half8 af1 = *(const half8*)(scr + rA1 * 32 + q * 8);
            const u16* bp = winp + ((size_t)(c * 4 + q) * 256 + mm) * 8;
#pragma unroll
            for (int nt = 0; nt < 16; ++nt) {
                half8 bf = *(const half8*)(bp + nt * 128);
                acc[0][nt] = MF(af0, bf, acc[0][nt]);
                acc[1][nt] = MF(af1, bf, acc[1][nt]);
            }
        }
        __syncthreads();
    }
    // epilogue -> h_s (own rows; no cross-wave hazard)
#pragma unroll
    for (int nt = 0; nt < 16; ++nt) {
        int cl = nt * 16 + mm;
        float bb = b_in[cl];
#pragma unroll
        for (int mt = 0; mt < 2; ++mt)
#pragma unroll
            for (int r = 0; r < 4; ++r) {
                int row = wave * 32 + mt * 16 + q * 4 + r;
                float v = fmaxf(acc[mt][nt][r] + bb, 0.f);
                union { u16 u; _Float16 h; } cc; cc.h = (_Float16)v;
                h_s[row * 264 + cl] = cc.u;
            }
    }

    // ================= layers =================
    for (int l = 0; l < 3; ++l) {
        // ---------- membership (from LDS h) ----------
        if (tid == 0) sfl = 0;
        __syncthreads();
        const u16* brow = pcB + ((size_t)(l * 16 + mm)) * 512;
        f32x4 macc[2];
        macc[0] = (f32x4){0.f, 0.f, 0.f, 0.f};
        macc[1] = (f32x4){0.f, 0.f, 0.f, 0.f};
#pragma unroll
        for (int g = 0; g < 2; ++g) {
            const u16* hrow = h_s + (size_t)(wave * 32 + g * 16 + mm) * 264;
#pragma unroll
            for (int it = 0; it < 16; ++it) {
                int kk = (it < 8 ? it : it - 8) * 32 + q * 8;
                half8 a = *(const half8*)(hrow + kk);
                if (it < 8) a = a * a;
                half8 b = *(const half8*)(brow + it * 32 + q * 8);
                macc[g] = MF(a, b, macc[g]);
            }
        }
        {
            float ccv = pccc[l * 16 + mm];
            bool any = false;
#pragma unroll
            for (int g = 0; g < 2; ++g)
#pragma unroll
                for (int r = 0; r < 4; ++r) {
                    float d = macc[g][r] + ccv;
                    float f = expf(-0.5f * d);
                    float s = f;
                    s += __shfl_xor(s, 1); s += __shfl_xor(s, 2);
                    s += __shfl_xor(s, 4); s += __shfl_xor(s, 8);
                    int lrow = wave * 32 + g * 16 + q * 4 + r;
                    union { u16 u; _Float16 h; } c2;
                    c2.h = (_Float16)(f / (s + 1e-12f));
                    mu_s[lrow * 16 + mm] = c2.u;
                    if (row0 + lrow < n && c2.u != 0) any = true;  // f16-visible only
                }
            if (__any(any) && lane == 0) atomicOr(&sfl, 1);
        }
        __syncthreads();
        const int blkfire = sfl;
        if (tid == 0 && blkfire) atomicOr(&gflag[l], 1);
        gbar();
        const int gf = atomicAdd(&gflag[l], 0);

        if (gf) {
            // ---- COLD PATH (uniform entry). write h16 for aggregation ----
#pragma unroll
            for (int it = 0; it < 16; ++it) {
                int idx = it * 256 + tid;
                int row = idx >> 5, cp = idx & 31;
                if (row < nr)
                    *(uint4*)(h16 + ((size_t)(row0 + row)) * 256 + cp * 8) =
                        *(const uint4*)(h_s + (size_t)row * 264 + cp * 8);
            }
            gbar();
            if (atomicAdd(done, 0) == 0) {           // build CSR once
                for (int e = bid * 256 + tid; e < E; e += nb * 256)
                    atomicAdd(&deg[edst[e]], 1);
                gbar();
                if (bid == 0) {                      // 256-thread scan
                    const int chunk = (n + 255) >> 8;
                    int s0 = tid * chunk, s1 = s0 + chunk;
                    if (s1 > n) s1 = n; if (s0 > n) s0 = n;
                    int tot = 0;
                    for (int i = s0; i < s1; ++i) tot += atomicAdd(&deg[i], 0);
                    int* sm = (int*)scr;
                    sm[tid] = tot; __syncthreads();
                    for (int off = 1; off < 256; off <<= 1) {
                        int t = (tid >= off) ? sm[tid - off] : 0;
                        __syncthreads(); sm[tid] += t; __syncthreads();
                    }
                    int base = sm[tid] - tot;
                    for (int i = s0; i < s1; ++i) {
                        int d = atomicAdd(&deg[i], 0);
                        indptr[i] = base; cursor[i] = base;
                        deginv[i] = 1.f / (float)(d > 1 ? d : 1);
                        base += d;
                    }
                    if (tid == 255) indptr[n] = sm[255];
                }
                gbar();
                for (int e = bid * 256 + tid; e < E; e += nb * 256) {
                    int d = edst[e];
                    int pos = atomicAdd(&cursor[d], 1);
                    ssrc[pos] = esrc[e];
                }
                gbar();
                if (bid == 0 && tid == 0) atomicExch(done, 1);
            }
            // aggregation: own rows, only if this block fired
            if (blkfire) {
                for (int node = row0 + wave; node < row0 + 128 && node < n; node += 4) {
                    int j0 = indptr[node], j1 = indptr[node + 1];
                    float a0 = 0, a1 = 0, a2 = 0, a3 = 0;
                    for (int j = j0; j < j1; ++j) {
                        int sN = ssrc[j];
                        unsigned long long raw = __hip_atomic_load(
                            (const unsigned long long*)(h16 + (size_t)sN * 256 + lane * 4),
                            __ATOMIC_RELAXED, __HIP_MEMORY_SCOPE_AGENT);
                        union { unsigned long long u; _Float16 h[4]; } hv; hv.u = raw;
                        a0 += (float)hv.h[0]; a1 += (float)hv.h[1];
                        a2 += (float)hv.h[2]; a3 += (float)hv.h[3];
                    }
                    float di = deginv[node];
                    union { uint2 u; _Float16 h[4]; } o;
                    o.h[0] = (_Float16)(a0 * di); o.h[1] = (_Float16)(a1 * di);
                    o.h[2] = (_Float16)(a2 * di); o.h[3] = (_Float16)(a3 * di);
                    *(uint2*)(agg16 + (size_t)node * 256 + lane * 4) = o.u;
                }
            }
            __syncthreads();
        }

        // ---------- self-GEMM: pre = [mu*agg | h | mu] @ Wcat ----------
        const u16* BpL = wcat + (size_t)l * 552 * 256 * 8;
        const float* bsl = b_self + l * 256;
#pragma unroll
        for (int i = 0; i < 2; ++i)
#pragma unroll
            for (int j = 0; j < 16; ++j) acc[i][j] = (f32x4){0.f, 0.f, 0.f, 0.f};

        if (gf && blkfire) {                         // fuzzy part (K 0..4095)
            int g0 = row0 + rA0; if (g0 >= n) g0 = n - 1;
            int g1 = row0 + rA1; if (g1 >= n) g1 = n - 1;
            const u16* ag0 = agg16 + (size_t)g0 * 256;
            const u16* ag1 = agg16 + (size_t)g1 * 256;
            const _Float16* mu0 = (const _Float16*)(mu_s + rA0 * 16);
            const _Float16* mu1 = (const _Float16*)(mu_s + rA1 * 16);
            for (int r = 0; r < 16; ++r) {
                _Float16 m0 = mu0[r], m1 = mu1[r];
#pragma unroll
                for (int kf = 0; kf < 8; ++kf) {
                    half8 af0 = *(const half8*)(ag0 + kf * 32 + q * 8) * m0;
                    half8 af1 = *(const half8*)(ag1 + kf * 32 + q * 8) * m1;
                    const u16* bp = BpL + ((size_t)((r * 32 + kf * 4 + q) * 256) + mm) * 8;
#pragma unroll
                    for (int nt = 0; nt < 16; ++nt) {
                        half8 bf = *(const half8*)(bp + nt * 128);
                        acc[0][nt] = MF(af0, bf, acc[0][nt]);
                        acc[1][nt] = MF(af1, bf, acc[1][nt]);
                    }
                }
            }
        }
        // h @ W_self (K 4096..4351) — always
#pragma unroll
        for (int kf = 0; kf < 8; ++kf) {
            half8 af0 = *(const half8*)(h_s + (size_t)rA0 * 264 + kf * 32 + q * 8);
            half8 af1 = *(const half8*)(h_s + (size_t)rA1 * 264 + kf * 32 + q * 8);
            const u16* bp = BpL + ((size_t)((512 + kf * 4 + q) * 256) + mm) * 8;
#pragma unroll
            for (int nt = 0; nt < 16; ++nt) {
                half8 bf = *(const half8*)(bp + nt * 128);
                acc[0][nt] = MF(af0, bf, acc[0][nt]);
                acc[1][nt] = MF(af1, bf, acc[1][nt]);
            }
        }
        if (gf && blkfire) {                         // mu @ b_rule (K 4352..4367)
            half8 a0 = (half8){0, 0, 0, 0, 0, 0, 0, 0};
            half8 a1 = (half8){0, 0, 0, 0, 0, 0, 0, 0};
            if (q < 2) {
                a0 = *(const half8*)(mu_s + rA0 * 16 + q * 8);
                a1 = *(const half8*)(mu_s + rA1 * 16 + q * 8);
            }
            const u16* bp = BpL + ((size_t)((544 + q) * 256) + mm) * 8;
#pragma unroll
            for (int nt = 0; nt < 16; ++nt) {
                half8 bf = *(const half8*)(bp + nt * 128);
                acc[0][nt] = MF(a0, bf, acc[0][nt]);
                acc[1][nt] = MF(a1, bf, acc[1][nt]);
            }
        }

        // ---------- BN column sums -> global atomics ----------
        float* bnb = (float*)scr;
        float* bnl = bnsum + l * 512;
#pragma unroll
        for (int nt = 0; nt < 16; ++nt) {
            int cl = nt * 16 + mm;
            float bb = bsl[cl];
            float s = 0.f, ss = 0.f;
#pragma unroll
            for (int mt = 0; mt < 2; ++mt)
#pragma unroll
                for (int r = 0; r < 4; ++r) {
                    int row = wave * 32 + mt * 16 + q * 4 + r;
                    float v = acc[mt][nt][r] + bb;
                    if (row < nr) { s += v; ss += v * v; }
                }
            s += __shfl_xor(s, 16);  s += __shfl_xor(s, 32);
            ss += __shfl_xor(ss, 16); ss += __shfl_xor(ss, 32);
            if (q == 0) {
                bnb[(wave * 256 + cl) * 2 + 0] = s;
                bnb[(wave * 256 + cl) * 2 + 1] = ss;
            }
        }
        __syncthreads();
        {
            float s  = bnb[tid * 2]       + bnb[(256 + tid) * 2]
                     + bnb[(512 + tid) * 2] + bnb[(768 + tid) * 2];
            float ss = bnb[tid * 2 + 1]   + bnb[(256 + tid) * 2 + 1]
                     + bnb[(512 + tid) * 2 + 1] + bnb[(768 + tid) * 2 + 1];
            atomicAdd(&bnl[tid], s);
            atomicAdd(&bnl[256 + tid], ss);
        }
        gbar();
        // ---------- alpha/shift + residual update in LDS ----------
        float* l_ab = (float*)scr;                   // overwrites bnb (consumed)
        {
            float su = atomicAdd(&bnl[tid], 0.f);
            float sq = atomicAdd(&bnl[256 + tid], 0.f);
            float invn = 1.f / (float)n;
            float m = su * invn;
            float al = gamma[l * 256 + tid] * rsqrtf(sq * invn - m * m + 1e-5f);
            l_ab[tid] = al;
            l_ab[256 + tid] = beta[l * 256 + tid] - m * al;
        }
        __syncthreads();
#pragma unroll
        for (int nt = 0; nt < 16; ++nt) {
            int cl = nt * 16 + mm;
            float bb = bsl[cl];
            float al = l_ab[cl], sh = l_ab[256 + cl];
#pragma unroll
            for (int mt = 0; mt < 2; ++mt)
#pragma unroll
                for (int r = 0; r < 4; ++r) {
                    int row = wave * 32 + mt * 16 + q * 4 + r;
                    union { u16 u; _Float16 h; } ph; ph.h = (_Float16)(acc[mt][nt][r] + bb);
                    union { u16 u; _Float16 h; } hv; hv.u = h_s[row * 264 + cl];
                    float v = (float)hv.h + fmaxf((float)ph.h * al + sh, 0.f);
                    union { u16 u; _Float16 h; } o; o.h = (_Float16)v;
                    h_s[row * 264 + cl] = o.u;
                }
        }
        __syncthreads();
    }

    // ================= head: q = relu(h @ W_h1 + b_h1); out = softmax(q @ W_h2 + b_h2) =================
    f32x4 hq[2][8];
#pragma unroll
    for (int i = 0; i < 2; ++i)
#pragma unroll
        for (int j = 0; j < 8; ++j) hq[i][j] = (f32x4){0.f, 0.f, 0.f, 0.f};
#pragma unroll
    for (int kf = 0; kf < 8; ++kf) {
        half8 af0 = *(const half8*)(h_s + (size_t)rA0 * 264 + kf * 32 + q * 8);
        half8 af1 = *(const half8*)(h_s + (size_t)rA1 * 264 + kf * 32 + q * 8);
        const u16* bp = wh1p + ((size_t)((kf * 4 + q) * 128) + mm) * 8;
#pragma unroll
        for (int nt = 0; nt < 8; ++nt) {
            half8 bf = *(const half8*)(bp + nt * 128);
            hq[0][nt] = MF(af0, bf, hq[0][nt]);
            hq[1][nt] = MF(af1, bf, hq[1][nt]);
        }
    }
    __syncthreads();                                 // h reads done before overwrite
#pragma unroll
    for (int nt = 0; nt < 8; ++nt) {
        int cl = nt * 16 + mm;
        float bb = b_h1[cl];
#pragma unroll
        for (int mt = 0; mt < 2; ++mt)
#pragma unroll
            for (int r = 0; r < 4; ++r) {
                int row = wave * 32 + mt * 16 + q * 4 + r;
                float v = fmaxf(hq[mt][nt][r] + bb, 0.f);
                union { u16 u; _Float16 h; } cc; cc.h = (_Float16)v;
                h_s[row * 264 + cl] = cc.u;          // q-tile reuses h region
            }
    }
    __syncthreads();
    {
        const bool c2ok = (mm < 8);
        float b0 = b_h2[mm], b1 = b_h2[16 + mm];
        float b2 = c2ok ? b_h2[32 + mm] : 0.f;
#pragma unroll
        for (int hh = 0; hh < 2; ++hh) {
            int rbase = hh * 64 + wave * 16;
            f32x4 hacc[3];
#pragma unroll
            for (int t = 0; t < 3; ++t) hacc[t] = (f32x4){0.f, 0.f, 0.f, 0.f};
#pragma unroll
            for (int c = 0; c < 4; ++c) {
                half8 a = *(const half8*)(h_s + (size_t)(rbase + mm) * 264 + c * 32 + q * 8);
#pragma unroll
                for (int t = 0; t < 3; ++t) {
                    half8 b = *(const half8*)(wh2p + ((size_t)(c * 4 + q) * 48 + t * 16 + mm) * 8);
                    hacc[t] = MF(a, b, hacc[t]);
                }
            }
#pragma unroll
            for (int r = 0; r < 4; ++r) {
                int node = row0 + rbase + q * 4 + r;
                float v0 = hacc[0][r] + b0;
                float v1 = hacc[1][r] + b1;
                float v2 = c2ok ? (hacc[2][r] + b2) : -3e38f;
                float m = fmaxf(fmaxf(v0, v1), v2);
                m = fmaxf(m, __shfl_xor(m, 1)); m = fmaxf(m, __shfl_xor(m, 2));
                m = fmaxf(m, __shfl_xor(m, 4)); m = fmaxf(m, __shfl_xor(m, 8));
                float e0 = expf(v0 - m), e1 = expf(v1 - m);
                float e2 = c2ok ? expf(v2 - m) : 0.f;
                float s = e0 + e1 + e2;
                s += __shfl_xor(s, 1); s += __shfl_xor(s, 2);
                s += __shfl_xor(s, 4); s += __shfl_xor(s, 8);
                float is = 1.f / s;
                if (node < n) {
                    float* op = outF + (size_t)node * 40;
                    op[mm] = e0 * is;
                    op[16 + mm] = e1 * is;
                    if (c2ok) op[32 + mm] = e2 * is;
                }
            }
        }
    }
}

// ===========================================================================
// Launch
// ===========================================================================

extern "C" void kernel_launch(void* const* d_in, const int* in_sizes, int n_in,
                              void* d_out, int out_size, void* d_ws, size_t ws_size,
                              hipStream_t stream) {
    const float* x       = (const float*)d_in[0];
    const int*   ei      = (const int*)d_in[1];
    const float* W_in    = (const float*)d_in[2];
    const float* b_in    = (const float*)d_in[3];
    const float* centers = (const float*)d_in[4];
    const float* logsig  = (const float*)d_in[5];
    const float* W_rule  = (const float*)d_in[6];
    const float* b_rule  = (const float*)d_in[7];
    const float* W_self  = (const float*)d_in[8];
    const float* b_self  = (const float*)d_in[9];
    const float* gamma   = (const float*)d_in[10];
    const float* beta    = (const float*)d_in[11];
    const float* W_h1    = (const float*)d_in[12];
    const float* b_h1    = (const float*)d_in[13];
    const float* W_h2    = (const float*)d_in[14];
    const float* b_h2    = (const float*)d_in[15];

    const int N = in_sizes[0] / 128;
    const int E = in_sizes[1] / 2;
    const int* e_src = ei;
    const int* e_dst = ei + E;

    char* w = (char*)d_ws;
    size_t off = 0;
    auto alloc = [&](size_t bytes) -> void* {
        void* p = w + off;
        off = (off + bytes + 255) & ~(size_t)255;
        return p;
    };

    const int gx = cdiv(N, 128);                 // 391 blocks <= 512 co-resident slots

    u16*   h16    = (u16*)  alloc((size_t)N * 256 * 2);
    u16*   agg16  = (u16*)  alloc((size_t)N * 256 * 2);
    u16*   wcat   = (u16*)  alloc((size_t)3 * 552 * 256 * 8 * 2);
    u16*   winp   = (u16*)  alloc((size_t)16 * 256 * 8 * 2);
    u16*   wh1p   = (u16*)  alloc((size_t)32 * 128 * 8 * 2);
    u16*   wh2p   = (u16*)  alloc((size_t)16 * 48 * 8 * 2);
    u16*   pcB    = (u16*)  alloc((size_t)48 * 512 * 2);
    float* pccc   = (float*)alloc((size_t)48 * 4);
    int*   indptr = (int*)  alloc((size_t)(N + 1) * 4);
    int*   cursor = (int*)  alloc((size_t)N * 4);
    float* deginv = (float*)alloc((size_t)N * 4);
    int*   ssrc   = (int*)  alloc((size_t)E * 4);
    // zero region: [deg N][gflag 4][bnsum 3*512][done, barctr, pad]
    const int nzero = N + 4 + 3 * 512 + 8;
    int*   zerob  = (int*)  alloc((size_t)nzero * 4);
    int*   deg    = zerob;
    int*   gflag  = zerob + N;
    float* bnsum  = (float*)(zerob + N + 4);
    int*   misc   = zerob + N + 4 + 3 * 512;
    int*   done   = misc;
    int*   barctr = misc + 1;

    const int Z = cdiv(nzero, 256);
    const int Wb = 3 * 552 * 256 * 8 / 256;   // 13248
    const int prep_grid = Z + Wb + 128 + 128 + 24 + 48;

    prep_k<<<prep_grid, 256, 0, stream>>>(W_rule, W_self, b_rule, W_in, W_h1, W_h2,
                                          centers, logsig, wcat, winp, wh1p, wh2p,
                                          pcB, pccc, zerob, nzero, Z, Wb);

    fused_k<<<gx, 256, 0, stream>>>(x, e_src, e_dst,
                                    winp, b_in, wcat, b_self, pcB, pccc,
                                    gamma, beta, wh1p, b_h1, wh2p, b_h2,
                                    (float*)d_out,
                                    h16, agg16, deg, indptr, cursor, deginv, ssrc,
                                    gflag, done, barctr, bnsum,
                                    E, N, gx);
}